// Round 1
// baseline (1210.013 us; speedup 1.0000x reference)
//
#include <hip/hip_runtime.h>
#include <math.h>

#define H_AA   20
#define H_PAD  22
#define EMB    484          // 22*22
#define KSZ    9
#define NB     8            // batch
#define NPOS   512          // n
#define KNBR   30           // k neighbors
#define SMUT   99
#define STOT   100          // SMUT + WT

// ---------------------------------------------------------------------------
// Kernel 1: per-batch setup.
//  - winner-j (last-write-wins) scatter map: jmap[b][p] = j or -1
//  - mask compaction (mask requires etab row channel0 != 0):
//      poslist[b][i] = p (ascending), rowidx[b][p] = i or -1, mcount[b] = m
// ---------------------------------------------------------------------------
__global__ void setup_kernel(const int* __restrict__ E_idx,
                             const int* __restrict__ mut_pos,
                             const float* __restrict__ etab,
                             int* __restrict__ jmap,
                             int* __restrict__ rowidx,
                             int* __restrict__ poslist,
                             int* __restrict__ mcount) {
    int b  = blockIdx.x;
    int mp = mut_pos[b];
    for (int p = threadIdx.x; p < NPOS; p += blockDim.x) jmap[b * NPOS + p] = -1;
    __syncthreads();
    int t = threadIdx.x;
    if (t < KNBR) {
        int nb = E_idx[(b * NPOS + mp) * KNBR + t];
        bool winner = true;
        for (int j2 = t + 1; j2 < KNBR; ++j2)
            if (E_idx[(b * NPOS + mp) * KNBR + j2] == nb) { winner = false; break; }
        if (winner) jmap[b * NPOS + nb] = t;   // unique per position
    }
    __syncthreads();
    if (t == 0) {
        int m = 0;
        for (int p = 0; p < NPOS; ++p) {
            int j = jmap[b * NPOS + p];
            bool masked = false;
            if (j >= 0) {
                float c0 = etab[(((size_t)(b * NPOS + mp)) * KNBR + j) * 400];
                masked = (c0 != 0.0f);   // mask = lin[:,:,0] != 0
            }
            if (masked) { poslist[b * 32 + m] = p; rowidx[b * NPOS + p] = m; ++m; }
            else        { rowidx[b * NPOS + p] = -1; }
        }
        mcount[b] = m;
    }
}

// ---------------------------------------------------------------------------
// Kernel 2: tiled transpose  dst[c*R + r] = src[r*C + c]
// ---------------------------------------------------------------------------
#define TDIM 32
__global__ void transpose_kernel(const float* __restrict__ src,
                                 float* __restrict__ dst, int R, int C) {
    __shared__ float tile[TDIM][TDIM + 1];
    int c0 = blockIdx.x * TDIM;
    int r0 = blockIdx.y * TDIM;
    for (int ty = threadIdx.y; ty < TDIM; ty += blockDim.y) {
        int r = r0 + ty, c = c0 + threadIdx.x;
        if (r < R && c < C) tile[ty][threadIdx.x] = src[(size_t)r * C + c];
    }
    __syncthreads();
    for (int ty = threadIdx.y; ty < TDIM; ty += blockDim.y) {
        int c = c0 + ty, r = r0 + threadIdx.x;
        if (r < R && c < C) dst[(size_t)c * R + r] = tile[threadIdx.x][ty];
    }
}

// ---------------------------------------------------------------------------
// Kernel 3: conv (o and att) evaluated ONLY at mask positions.
//  o[b][i][ch] = b_f[ch] + sum_{d=-4..4, q=p+d scattered} W_f[ch][:][d+4]·row(q)
//  Wt layout: [in_ch][tap][out_ch]  (in_ch is padded 22*r+cc index)
// ---------------------------------------------------------------------------
__global__ void conv_kernel(const float* __restrict__ etab,
                            const float* __restrict__ Wtf,
                            const float* __restrict__ Wta,
                            const float* __restrict__ b_f,
                            const float* __restrict__ b_a,
                            const int* __restrict__ mut_pos,
                            const int* __restrict__ jmap,
                            const int* __restrict__ poslist,
                            const int* __restrict__ mcount,
                            float* __restrict__ o_out,
                            float* __restrict__ a_out) {
    int b = blockIdx.x / KNBR;
    int i = blockIdx.x % KNBR;
    if (i >= mcount[b]) return;           // block-uniform
    int p  = poslist[b * 32 + i];
    int mp = mut_pos[b];
    __shared__ float row[400];
    int ch = threadIdx.x;                 // 512 threads, ch<484 active
    double acc_o = (ch < EMB) ? (double)b_f[ch] : 0.0;
    double acc_a = (ch < EMB) ? (double)b_a[ch] : 0.0;
    for (int d = -4; d <= 4; ++d) {
        int q = p + d;
        if (q < 0 || q >= NPOS) continue;         // block-uniform
        int j = jmap[b * NPOS + q];
        if (j < 0) continue;                      // block-uniform
        __syncthreads();
        if (ch < 400)
            row[ch] = etab[(((size_t)(b * NPOS + mp)) * KNBR + j) * 400 + ch];
        __syncthreads();
        if (ch < EMB) {
            int tap = d + 4;
            for (int r = 0; r < H_AA; ++r) {
                for (int cc = 0; cc < H_AA; ++cc) {
                    int in_ch = r * H_PAD + cc;
                    float x = row[r * H_AA + cc];
                    size_t base = ((size_t)in_ch * KSZ + tap) * EMB + ch;
                    acc_o += (double)Wtf[base] * (double)x;
                    acc_a += (double)Wta[base] * (double)x;
                }
            }
        }
    }
    if (ch < EMB) {
        o_out[((size_t)b * KNBR + i) * EMB + ch] = (float)acc_o;
        a_out[((size_t)b * KNBR + i) * EMB + ch] = (float)acc_a;
    }
}

// ---------------------------------------------------------------------------
// Kernel 4: per-(b,ch) softmax over the m mask positions; la = o * softmax(att)
// (off-mask positions have softmax weight exactly 0 in fp32)
// ---------------------------------------------------------------------------
__global__ void softmax_kernel(const float* __restrict__ o,
                               const float* __restrict__ att,
                               const int* __restrict__ mcount,
                               float* __restrict__ la) {
    int b  = blockIdx.x;
    int ch = threadIdx.x;
    if (ch >= EMB) return;
    int m = mcount[b];
    float mx = -1e30f;
    for (int i = 0; i < m; ++i)
        mx = fmaxf(mx, att[((size_t)b * KNBR + i) * EMB + ch]);
    double sum = 0.0;
    for (int i = 0; i < m; ++i)
        sum += (double)expf(att[((size_t)b * KNBR + i) * EMB + ch] - mx);
    for (int i = 0; i < m; ++i) {
        size_t idx = ((size_t)b * KNBR + i) * EMB + ch;
        float w = (float)((double)expf(att[idx] - mx) / sum);
        la[idx] = o[idx] * w;
    }
}

// ---------------------------------------------------------------------------
// Kernel 5: both_out MLP + ddg affine on the mask rows; last block = background
// row (la = 0 path shared by every non-mask position).
//  y1 = relu(la)@W1^T + b1 ; y2 = relu(y1)@W2^T + b2 ; ddg = y2*w + b
// ---------------------------------------------------------------------------
__global__ void mlp_kernel(const float* __restrict__ la,
                           const float* __restrict__ W1t,
                           const float* __restrict__ b1,
                           const float* __restrict__ W2t,
                           const float* __restrict__ b2,
                           const float* __restrict__ w_ddg,
                           const float* __restrict__ b_ddg,
                           const int* __restrict__ mcount,
                           float* __restrict__ rows_out,
                           float* __restrict__ bg) {
    __shared__ float buf[EMB];
    int blk  = blockIdx.x;
    bool isbg = (blk == NB * KNBR);
    int b = blk / KNBR, i = blk % KNBR;
    if (!isbg && i >= mcount[b]) return;  // block-uniform
    int ch = threadIdx.x;
    if (ch < EMB)
        buf[ch] = isbg ? 0.0f : fmaxf(la[((size_t)b * KNBR + i) * EMB + ch], 0.0f);
    __syncthreads();
    double acc = (ch < EMB) ? (double)b1[ch] : 0.0;
    if (ch < EMB)
        for (int in = 0; in < EMB; ++in)
            acc += (double)W1t[(size_t)in * EMB + ch] * (double)buf[in];
    float y1 = fmaxf((float)acc, 0.0f);   // round like the fp32 reference, then relu
    __syncthreads();
    if (ch < EMB) buf[ch] = y1;
    __syncthreads();
    double acc2 = (ch < EMB) ? (double)b2[ch] : 0.0;
    if (ch < EMB)
        for (int in = 0; in < EMB; ++in)
            acc2 += (double)W2t[(size_t)in * EMB + ch] * (double)buf[in];
    if (ch < EMB) {
        float y2 = (float)acc2;
        float dd = y2 * w_ddg[0] + b_ddg[0];
        if (isbg) bg[ch] = dd;
        else      rows_out[((size_t)b * KNBR + i) * EMB + ch] = dd;
    }
}

// ---------------------------------------------------------------------------
// Kernel 6: scores[b][s] = sum_j etab2[b, j, a, c_j]   (one wave per (b,s))
//  a = seq[b,s,mut_pos[b]] ; mask rows from rows_out, others from bg.
// ---------------------------------------------------------------------------
__global__ void score_kernel(const int* __restrict__ sortc,
                             const int* __restrict__ seqs,
                             const int* __restrict__ mut_pos,
                             const int* __restrict__ rowidx,
                             const float* __restrict__ rows,
                             const float* __restrict__ bg,
                             double* __restrict__ scoresD) {
    int blk = blockIdx.x;                 // 800 = 8 * 100
    int b = blk / STOT, s = blk % STOT;
    int mp = mut_pos[b];
    int a = (s < SMUT) ? sortc[((size_t)b * SMUT + s) * NPOS + mp]
                       : seqs[b * NPOS + mp];
    int lane = threadIdx.x;               // 64
    double acc = 0.0;
    for (int j = lane; j < NPOS; j += 64) {
        int c = (s < SMUT) ? sortc[((size_t)b * SMUT + s) * NPOS + j]
                           : seqs[b * NPOS + j];
        int i = rowidx[b * NPOS + j];
        float v = (i >= 0) ? rows[((size_t)b * KNBR + i) * EMB + a * H_PAD + c]
                           : bg[a * H_PAD + c];
        acc += (double)v;
    }
    for (int off = 32; off > 0; off >>= 1)
        acc += __shfl_down(acc, off, 64);
    if (lane == 0) scoresD[blk] = acc;
}

// ---------------------------------------------------------------------------
// Kernel 7: out[b][s] = scores[b][s] - scores[b][WT],  s < 99
// ---------------------------------------------------------------------------
__global__ void final_kernel(const double* __restrict__ scoresD,
                             float* __restrict__ out) {
    int idx = blockIdx.x * blockDim.x + threadIdx.x;
    if (idx >= NB * SMUT) return;
    int b = idx / SMUT, s = idx % SMUT;
    out[idx] = (float)(scoresD[b * STOT + s] - scoresD[b * STOT + SMUT]);
}

// ---------------------------------------------------------------------------
extern "C" void kernel_launch(void* const* d_in, const int* in_sizes, int n_in,
                              void* d_out, int out_size, void* d_ws, size_t ws_size,
                              hipStream_t stream) {
    const float* etab = (const float*)d_in[0];
    const int*   E_idx = (const int*)d_in[1];
    const int*   sortc = (const int*)d_in[2];
    const int*   seqs  = (const int*)d_in[3];
    const int*   mutp  = (const int*)d_in[4];
    // d_in[5] = nodes (unused)
    const float* W_f = (const float*)d_in[6];
    const float* b_f = (const float*)d_in[7];
    const float* W_a = (const float*)d_in[8];
    const float* b_a = (const float*)d_in[9];
    const float* W1  = (const float*)d_in[10];
    const float* b1  = (const float*)d_in[11];
    const float* W2  = (const float*)d_in[12];
    const float* b2  = (const float*)d_in[13];
    const float* wdd = (const float*)d_in[14];
    const float* bdd = (const float*)d_in[15];
    float* out = (float*)d_out;

    char* wsb = (char*)d_ws;
    size_t off = 0;
    auto alloc = [&](size_t bytes) -> void* {
        void* p = wsb + off;
        off = (off + bytes + 255) & ~((size_t)255);
        return p;
    };
    float*  Wtf     = (float*)alloc((size_t)EMB * EMB * KSZ * 4);
    float*  Wta     = (float*)alloc((size_t)EMB * EMB * KSZ * 4);
    float*  W1t     = (float*)alloc((size_t)EMB * EMB * 4);
    float*  W2t     = (float*)alloc((size_t)EMB * EMB * 4);
    int*    jmap    = (int*)alloc((size_t)NB * NPOS * 4);
    int*    rowidx  = (int*)alloc((size_t)NB * NPOS * 4);
    int*    poslist = (int*)alloc((size_t)NB * 32 * 4);
    int*    mcount  = (int*)alloc((size_t)NB * 4);
    float*  o_buf   = (float*)alloc((size_t)NB * KNBR * EMB * 4);
    float*  a_buf   = (float*)alloc((size_t)NB * KNBR * EMB * 4);
    float*  la_buf  = (float*)alloc((size_t)NB * KNBR * EMB * 4);
    float*  rows    = (float*)alloc((size_t)NB * KNBR * EMB * 4);
    float*  bg      = (float*)alloc((size_t)EMB * 4);
    double* scoresD = (double*)alloc((size_t)NB * STOT * 8);
    (void)ws_size; (void)in_sizes; (void)n_in; (void)out_size;

    setup_kernel<<<NB, 512, 0, stream>>>(E_idx, mutp, etab, jmap, rowidx, poslist, mcount);

    dim3 tb(TDIM, 8);
    {   // W_f, W_a: [484][484*9] -> [in*9+k][out]
        dim3 g((EMB * KSZ + TDIM - 1) / TDIM, (EMB + TDIM - 1) / TDIM);
        transpose_kernel<<<g, tb, 0, stream>>>(W_f, Wtf, EMB, EMB * KSZ);
        transpose_kernel<<<g, tb, 0, stream>>>(W_a, Wta, EMB, EMB * KSZ);
    }
    {   // W1, W2: [484][484] -> [in][out]
        dim3 g((EMB + TDIM - 1) / TDIM, (EMB + TDIM - 1) / TDIM);
        transpose_kernel<<<g, tb, 0, stream>>>(W1, W1t, EMB, EMB);
        transpose_kernel<<<g, tb, 0, stream>>>(W2, W2t, EMB, EMB);
    }

    conv_kernel<<<NB * KNBR, 512, 0, stream>>>(etab, Wtf, Wta, b_f, b_a, mutp,
                                               jmap, poslist, mcount, o_buf, a_buf);
    softmax_kernel<<<NB, 512, 0, stream>>>(o_buf, a_buf, mcount, la_buf);
    mlp_kernel<<<NB * KNBR + 1, 512, 0, stream>>>(la_buf, W1t, b1, W2t, b2, wdd, bdd,
                                                  mcount, rows, bg);
    score_kernel<<<NB * STOT, 64, 0, stream>>>(sortc, seqs, mutp, rowidx, rows, bg, scoresD);
    final_kernel<<<(NB * SMUT + 255) / 256, 256, 0, stream>>>(scoresD, out);
}

// Round 2
// 418.610 us; speedup vs baseline: 2.8905x; 2.8905x over previous
//
#include <hip/hip_runtime.h>
#include <math.h>

#define H_AA   20
#define H_PAD  22
#define EMB    484          // 22*22
#define KSZ    9
#define NB     8            // batch
#define NPOS   512          // n
#define KNBR   30           // k neighbors
#define SMUT   99
#define STOT   100          // SMUT + WT
#define MAXPAIR 288         // >= KNBR*9
#define ROWS   (NB*KNBR)    // 240

// ---------------------------------------------------------------------------
// Kernel 1: per-batch setup (fully parallel).
//  - winner-j (last-write-wins) scatter map jmap[p] (LDS then global)
//  - mask flags + ballot/popcount prefix scan -> rowidx, mcount
//  - pair list: for each masked p, each tap d with jmap[p+d]>=0 ->
//      packed (rowidx<<10 | tap<<5 | j)
// ---------------------------------------------------------------------------
__global__ void setup_kernel(const int* __restrict__ E_idx,
                             const int* __restrict__ mut_pos,
                             const float* __restrict__ etab,
                             int* __restrict__ jmap_g,
                             int* __restrict__ rowidx_g,
                             int* __restrict__ mcount,
                             int* __restrict__ pairs,
                             int* __restrict__ npairs) {
    int b  = blockIdx.x;
    int mp = mut_pos[b];
    __shared__ int jmap[NPOS];
    __shared__ int wcnt[8], wbase[8];
    __shared__ int paircnt;
    int t = threadIdx.x;                 // 512 threads
    jmap[t] = -1;
    if (t == 0) paircnt = 0;
    __syncthreads();
    if (t < KNBR) {
        int nb = E_idx[(b * NPOS + mp) * KNBR + t];
        bool winner = true;
        for (int j2 = t + 1; j2 < KNBR; ++j2)
            if (E_idx[(b * NPOS + mp) * KNBR + j2] == nb) { winner = false; break; }
        if (winner) jmap[nb] = t;        // unique per position
    }
    __syncthreads();
    int j = jmap[t];
    int f = 0;
    if (j >= 0) {
        float c0 = etab[(((size_t)(b * NPOS + mp)) * KNBR + j) * 400];
        f = (c0 != 0.0f) ? 1 : 0;        // mask = lin[:,:,0] != 0
    }
    jmap_g[b * NPOS + t] = j;
    unsigned long long bal = __ballot(f);
    int lane = t & 63, w = t >> 6;
    if (lane == 0) wcnt[w] = __popcll(bal);
    __syncthreads();
    if (t == 0) {
        int s = 0;
        for (int ww = 0; ww < 8; ++ww) { wbase[ww] = s; s += wcnt[ww]; }
        mcount[b] = s;
    }
    __syncthreads();
    int ridx = -1;
    if (f) ridx = wbase[w] + __popcll(bal & ((1ull << lane) - 1ull));
    rowidx_g[b * NPOS + t] = ridx;
    if (f) {
        for (int d = -4; d <= 4; ++d) {
            int q = t + d;
            if (q < 0 || q >= NPOS) continue;
            int jq = jmap[q];
            if (jq < 0) continue;
            int idx = atomicAdd(&paircnt, 1);
            pairs[b * MAXPAIR + idx] = (ridx << 10) | ((d + 4) << 5) | jq;
        }
    }
    __syncthreads();
    if (t == 0) npairs[b] = paircnt;
}

// ---------------------------------------------------------------------------
// Kernel 2: tiled transpose  dst[c*R + r] = src[r*C + c]
// ---------------------------------------------------------------------------
#define TDIM 32
__global__ void transpose_kernel(const float* __restrict__ src,
                                 float* __restrict__ dst, int R, int C) {
    __shared__ float tile[TDIM][TDIM + 1];
    int c0 = blockIdx.x * TDIM;
    int r0 = blockIdx.y * TDIM;
    for (int ty = threadIdx.y; ty < TDIM; ty += blockDim.y) {
        int r = r0 + ty, c = c0 + threadIdx.x;
        if (r < R && c < C) tile[ty][threadIdx.x] = src[(size_t)r * C + c];
    }
    __syncthreads();
    for (int ty = threadIdx.y; ty < TDIM; ty += blockDim.y) {
        int c = c0 + ty, r = r0 + threadIdx.x;
        if (r < R && c < C) dst[(size_t)c * R + r] = tile[threadIdx.x][ty];
    }
}

// ---------------------------------------------------------------------------
// Kernel 3: init f64 conv accumulators with biases
// ---------------------------------------------------------------------------
__global__ void init_oa_kernel(const float* __restrict__ b_f,
                               const float* __restrict__ b_a,
                               double* __restrict__ o_d,
                               double* __restrict__ a_d) {
    int idx = blockIdx.x * blockDim.x + threadIdx.x;
    const int N = ROWS * EMB;
    if (idx < N)            o_d[idx]     = (double)b_f[idx % EMB];
    else if (idx < 2 * N)   a_d[idx - N] = (double)b_a[(idx - N) % EMB];
}

// ---------------------------------------------------------------------------
// Kernel 4: conv, one block per valid (row, tap, neighbor) pair.
//  threads 0-127: o (float4 out-chunks), threads 128-255: att.
//  Wt layout: [in_ch*9 + tap][out] (row = 484 floats = 121 float4, 16B aligned)
//  f64 atomicAdd partials into bias-initialized o_d / a_d.
// ---------------------------------------------------------------------------
__global__ void conv_pair_kernel(const float* __restrict__ etab,
                                 const float* __restrict__ Wtf,
                                 const float* __restrict__ Wta,
                                 const int* __restrict__ mut_pos,
                                 const int* __restrict__ pairs,
                                 const int* __restrict__ npairs,
                                 double* __restrict__ o_d,
                                 double* __restrict__ a_d) {
    int b    = blockIdx.x / MAXPAIR;
    int pidx = blockIdx.x % MAXPAIR;
    if (pidx >= npairs[b]) return;       // block-uniform
    int pk  = pairs[b * MAXPAIR + pidx];
    int i   = pk >> 10;
    int tap = (pk >> 5) & 31;
    int j   = pk & 31;
    int mp  = mut_pos[b];
    __shared__ float xs[400];
    int t = threadIdx.x;                 // 256
    const float* src = etab + (((size_t)(b * NPOS + mp)) * KNBR + j) * 400;
    for (int u = t; u < 400; u += 256) xs[u] = src[u];
    __syncthreads();
    int half = t >> 7, c4 = t & 127;
    if (c4 >= 121) return;
    const float* W = half ? Wta : Wtf;
    double a0 = 0, a1 = 0, a2 = 0, a3 = 0;
    for (int r = 0; r < H_AA; ++r) {
        #pragma unroll 4
        for (int cc = 0; cc < H_AA; ++cc) {
            int in = r * H_PAD + cc;
            float4 wv = *(reinterpret_cast<const float4*>(
                              W + (size_t)(in * KSZ + tap) * EMB) + c4);
            float xv = xs[r * H_AA + cc];
            a0 += (double)wv.x * xv; a1 += (double)wv.y * xv;
            a2 += (double)wv.z * xv; a3 += (double)wv.w * xv;
        }
    }
    double* dst = (half ? a_d : o_d) + ((size_t)(b * KNBR + i)) * EMB + c4 * 4;
    atomicAdd(dst + 0, a0); atomicAdd(dst + 1, a1);
    atomicAdd(dst + 2, a2); atomicAdd(dst + 3, a3);
}

// ---------------------------------------------------------------------------
// Kernel 5: per-(b,ch) softmax over m mask positions; la = o * softmax(att)
// ---------------------------------------------------------------------------
__global__ void softmax_kernel(const double* __restrict__ o_d,
                               const double* __restrict__ a_d,
                               const int* __restrict__ mcount,
                               float* __restrict__ la) {
    int idx = blockIdx.x * blockDim.x + threadIdx.x;
    if (idx >= NB * EMB) return;
    int b = idx / EMB, ch = idx % EMB;
    int m = mcount[b];
    float mx = -1e30f;
    for (int i = 0; i < m; ++i)
        mx = fmaxf(mx, (float)a_d[((size_t)(b * KNBR + i)) * EMB + ch]);
    double sum = 0.0;
    for (int i = 0; i < m; ++i)
        sum += (double)expf((float)a_d[((size_t)(b * KNBR + i)) * EMB + ch] - mx);
    for (int i = 0; i < m; ++i) {
        size_t o = ((size_t)(b * KNBR + i)) * EMB + ch;
        float w = (float)((double)expf((float)a_d[o] - mx) / sum);
        la[o] = (float)o_d[o] * w;
    }
}

// ---------------------------------------------------------------------------
// Kernel 6: fused both_out MLP + ddg affine, one block per row (+1 background).
//  512 threads: 4-way K-split x 121 float4 out-chunks, f64 LDS reduce.
// ---------------------------------------------------------------------------
__global__ void mlp_kernel(const float* __restrict__ la,
                           const float* __restrict__ W1t,
                           const float* __restrict__ b1,
                           const float* __restrict__ W2t,
                           const float* __restrict__ b2,
                           const float* __restrict__ w_ddg,
                           const float* __restrict__ b_ddg,
                           const int* __restrict__ mcount,
                           float* __restrict__ rows_out,
                           float* __restrict__ bg) {
    __shared__ float  xs[EMB];
    __shared__ double red[4 * EMB];
    int blk  = blockIdx.x;
    bool isbg = (blk == ROWS);
    int b = blk / KNBR, i = blk % KNBR;
    if (!isbg && i >= mcount[b]) return; // block-uniform
    int t  = threadIdx.x;                // 512
    int q  = t >> 7, c4 = t & 127;
    for (int u = t; u < EMB; u += 512)
        xs[u] = isbg ? 0.0f : fmaxf(la[((size_t)(b * KNBR + i)) * EMB + u], 0.0f);
    __syncthreads();
    // ---- layer 1 ----
    if (c4 < 121) {
        double a0 = 0, a1 = 0, a2 = 0, a3 = 0;
        int u0 = q * 121;
        #pragma unroll 4
        for (int u = u0; u < u0 + 121; ++u) {
            float4 wv = *(reinterpret_cast<const float4*>(W1t + (size_t)u * EMB) + c4);
            float xv = xs[u];
            a0 += (double)wv.x * xv; a1 += (double)wv.y * xv;
            a2 += (double)wv.z * xv; a3 += (double)wv.w * xv;
        }
        red[q * EMB + c4 * 4 + 0] = a0; red[q * EMB + c4 * 4 + 1] = a1;
        red[q * EMB + c4 * 4 + 2] = a2; red[q * EMB + c4 * 4 + 3] = a3;
    }
    __syncthreads();
    float y1f = 0.0f;
    if (t < EMB) {
        double y = (double)b1[t] + red[t] + red[EMB + t] + red[2 * EMB + t] + red[3 * EMB + t];
        y1f = fmaxf((float)y, 0.0f);
    }
    __syncthreads();                     // reads of red/xs done
    if (t < EMB) xs[t] = y1f;
    __syncthreads();
    // ---- layer 2 ----
    if (c4 < 121) {
        double a0 = 0, a1 = 0, a2 = 0, a3 = 0;
        int u0 = q * 121;
        #pragma unroll 4
        for (int u = u0; u < u0 + 121; ++u) {
            float4 wv = *(reinterpret_cast<const float4*>(W2t + (size_t)u * EMB) + c4);
            float xv = xs[u];
            a0 += (double)wv.x * xv; a1 += (double)wv.y * xv;
            a2 += (double)wv.z * xv; a3 += (double)wv.w * xv;
        }
        red[q * EMB + c4 * 4 + 0] = a0; red[q * EMB + c4 * 4 + 1] = a1;
        red[q * EMB + c4 * 4 + 2] = a2; red[q * EMB + c4 * 4 + 3] = a3;
    }
    __syncthreads();
    if (t < EMB) {
        double y = (double)b2[t] + red[t] + red[EMB + t] + red[2 * EMB + t] + red[3 * EMB + t];
        float dd = (float)y * w_ddg[0] + b_ddg[0];
        if (isbg) bg[t] = dd;
        else      rows_out[((size_t)(b * KNBR + i)) * EMB + t] = dd;
    }
}

// ---------------------------------------------------------------------------
// Kernel 7: scores[b][s] = sum_j etab2[b, j, a, c_j]   (one wave per (b,s))
// ---------------------------------------------------------------------------
__global__ void score_kernel(const int* __restrict__ sortc,
                             const int* __restrict__ seqs,
                             const int* __restrict__ mut_pos,
                             const int* __restrict__ rowidx,
                             const float* __restrict__ rows,
                             const float* __restrict__ bg,
                             double* __restrict__ scoresD) {
    int blk = blockIdx.x;                 // 800 = 8 * 100
    int b = blk / STOT, s = blk % STOT;
    int mp = mut_pos[b];
    int a = (s < SMUT) ? sortc[((size_t)b * SMUT + s) * NPOS + mp]
                       : seqs[b * NPOS + mp];
    int lane = threadIdx.x;               // 64
    double acc = 0.0;
    for (int j = lane; j < NPOS; j += 64) {
        int c = (s < SMUT) ? sortc[((size_t)b * SMUT + s) * NPOS + j]
                           : seqs[b * NPOS + j];
        int i = rowidx[b * NPOS + j];
        float v = (i >= 0) ? rows[((size_t)(b * KNBR + i)) * EMB + a * H_PAD + c]
                           : bg[a * H_PAD + c];
        acc += (double)v;
    }
    for (int off = 32; off > 0; off >>= 1)
        acc += __shfl_down(acc, off, 64);
    if (lane == 0) scoresD[blk] = acc;
}

// ---------------------------------------------------------------------------
// Kernel 8: out[b][s] = scores[b][s] - scores[b][WT],  s < 99
// ---------------------------------------------------------------------------
__global__ void final_kernel(const double* __restrict__ scoresD,
                             float* __restrict__ out) {
    int idx = blockIdx.x * blockDim.x + threadIdx.x;
    if (idx >= NB * SMUT) return;
    int b = idx / SMUT, s = idx % SMUT;
    out[idx] = (float)(scoresD[b * STOT + s] - scoresD[b * STOT + SMUT]);
}

// ---------------------------------------------------------------------------
extern "C" void kernel_launch(void* const* d_in, const int* in_sizes, int n_in,
                              void* d_out, int out_size, void* d_ws, size_t ws_size,
                              hipStream_t stream) {
    const float* etab = (const float*)d_in[0];
    const int*   E_idx = (const int*)d_in[1];
    const int*   sortc = (const int*)d_in[2];
    const int*   seqs  = (const int*)d_in[3];
    const int*   mutp  = (const int*)d_in[4];
    // d_in[5] = nodes (unused)
    const float* W_f = (const float*)d_in[6];
    const float* b_f = (const float*)d_in[7];
    const float* W_a = (const float*)d_in[8];
    const float* b_a = (const float*)d_in[9];
    const float* W1  = (const float*)d_in[10];
    const float* b1  = (const float*)d_in[11];
    const float* W2  = (const float*)d_in[12];
    const float* b2  = (const float*)d_in[13];
    const float* wdd = (const float*)d_in[14];
    const float* bdd = (const float*)d_in[15];
    float* out = (float*)d_out;

    char* wsb = (char*)d_ws;
    size_t off = 0;
    auto alloc = [&](size_t bytes) -> void* {
        void* p = wsb + off;
        off = (off + bytes + 255) & ~((size_t)255);
        return p;
    };
    float*  Wtf     = (float*)alloc((size_t)EMB * EMB * KSZ * 4);
    float*  Wta     = (float*)alloc((size_t)EMB * EMB * KSZ * 4);
    float*  W1t     = (float*)alloc((size_t)EMB * EMB * 4);
    float*  W2t     = (float*)alloc((size_t)EMB * EMB * 4);
    int*    jmap    = (int*)alloc((size_t)NB * NPOS * 4);
    int*    rowidx  = (int*)alloc((size_t)NB * NPOS * 4);
    int*    mcount  = (int*)alloc((size_t)NB * 4);
    int*    pairs   = (int*)alloc((size_t)NB * MAXPAIR * 4);
    int*    npairs  = (int*)alloc((size_t)NB * 4);
    double* o_d     = (double*)alloc((size_t)ROWS * EMB * 8);
    double* a_d     = (double*)alloc((size_t)ROWS * EMB * 8);
    float*  la_buf  = (float*)alloc((size_t)ROWS * EMB * 4);
    float*  rows    = (float*)alloc((size_t)ROWS * EMB * 4);
    float*  bg      = (float*)alloc((size_t)EMB * 4);
    double* scoresD = (double*)alloc((size_t)NB * STOT * 8);
    (void)ws_size; (void)in_sizes; (void)n_in; (void)out_size;

    setup_kernel<<<NB, 512, 0, stream>>>(E_idx, mutp, etab, jmap, rowidx,
                                         mcount, pairs, npairs);

    dim3 tb(TDIM, 8);
    {   // W_f, W_a: [484][484*9] -> [in*9+k][out]
        dim3 g((EMB * KSZ + TDIM - 1) / TDIM, (EMB + TDIM - 1) / TDIM);
        transpose_kernel<<<g, tb, 0, stream>>>(W_f, Wtf, EMB, EMB * KSZ);
        transpose_kernel<<<g, tb, 0, stream>>>(W_a, Wta, EMB, EMB * KSZ);
    }
    {   // W1, W2: [484][484] -> [in][out]
        dim3 g((EMB + TDIM - 1) / TDIM, (EMB + TDIM - 1) / TDIM);
        transpose_kernel<<<g, tb, 0, stream>>>(W1, W1t, EMB, EMB);
        transpose_kernel<<<g, tb, 0, stream>>>(W2, W2t, EMB, EMB);
    }

    init_oa_kernel<<<(2 * ROWS * EMB + 255) / 256, 256, 0, stream>>>(b_f, b_a, o_d, a_d);
    conv_pair_kernel<<<NB * MAXPAIR, 256, 0, stream>>>(etab, Wtf, Wta, mutp,
                                                       pairs, npairs, o_d, a_d);
    softmax_kernel<<<(NB * EMB + 255) / 256, 256, 0, stream>>>(o_d, a_d, mcount, la_buf);
    mlp_kernel<<<ROWS + 1, 512, 0, stream>>>(la_buf, W1t, b1, W2t, b2, wdd, bdd,
                                             mcount, rows, bg);
    score_kernel<<<NB * STOT, 64, 0, stream>>>(sortc, seqs, mutp, rowidx, rows, bg, scoresD);
    final_kernel<<<(NB * SMUT + 255) / 256, 256, 0, stream>>>(scoresD, out);
}